// Round 1
// baseline (146.545 us; speedup 1.0000x reference)
//
#include <hip/hip_runtime.h>

// SATD-style loss: sum(|H8 @ (orig - pred)|) over [524288, 3, 8, 8] fp32 blocks.
// Memory-bound: 805 MB read, scalar out. Each thread handles 4 columns (w-half)
// of one 8x8 channel-block via float4 row loads; FWHT-8 along rows in registers.

__device__ __forceinline__ float4 f4add(float4 a, float4 b) {
    return make_float4(a.x + b.x, a.y + b.y, a.z + b.z, a.w + b.w);
}
__device__ __forceinline__ float4 f4sub(float4 a, float4 b) {
    return make_float4(a.x - b.x, a.y - b.y, a.z - b.z, a.w - b.w);
}
__device__ __forceinline__ float f4abssum(float4 a) {
    return fabsf(a.x) + fabsf(a.y) + fabsf(a.z) + fabsf(a.w);
}

__global__ __launch_bounds__(256) void satd_loss_kernel(
        const float* __restrict__ orig, const float* __restrict__ pred,
        float* __restrict__ out, int nwork) {
    const int tid = blockIdx.x * blockDim.x + threadIdx.x;
    const int gstride = gridDim.x * blockDim.x;

    float acc = 0.0f;

    for (int i = tid; i < nwork; i += gstride) {
        // work item i -> channel-block (i>>1), column half (i&1): columns w = half*4 .. half*4+3
        const int base = (i >> 1) * 64 + (i & 1) * 4;

        float4 d0, d1, d2, d3, d4, d5, d6, d7;
        {
            const float4* o = reinterpret_cast<const float4*>(orig + base);
            const float4* p = reinterpret_cast<const float4*>(pred + base);
            // rows are 8 floats apart = 2 float4s apart
            d0 = f4sub(o[0],  p[0]);
            d1 = f4sub(o[2],  p[2]);
            d2 = f4sub(o[4],  p[4]);
            d3 = f4sub(o[6],  p[6]);
            d4 = f4sub(o[8],  p[8]);
            d5 = f4sub(o[10], p[10]);
            d6 = f4sub(o[12], p[12]);
            d7 = f4sub(o[14], p[14]);
        }

        // 8-point FWHT along rows (abs-sum is ordering-invariant)
        float4 a0 = f4add(d0, d1), a1 = f4sub(d0, d1);
        float4 a2 = f4add(d2, d3), a3 = f4sub(d2, d3);
        float4 a4 = f4add(d4, d5), a5 = f4sub(d4, d5);
        float4 a6 = f4add(d6, d7), a7 = f4sub(d6, d7);

        float4 b0 = f4add(a0, a2), b2 = f4sub(a0, a2);
        float4 b1 = f4add(a1, a3), b3 = f4sub(a1, a3);
        float4 b4 = f4add(a4, a6), b6 = f4sub(a4, a6);
        float4 b5 = f4add(a5, a7), b7 = f4sub(a5, a7);

        float4 c0 = f4add(b0, b4), c4 = f4sub(b0, b4);
        float4 c1 = f4add(b1, b5), c5 = f4sub(b1, b5);
        float4 c2 = f4add(b2, b6), c6 = f4sub(b2, b6);
        float4 c3 = f4add(b3, b7), c7 = f4sub(b3, b7);

        acc += f4abssum(c0) + f4abssum(c1) + f4abssum(c2) + f4abssum(c3)
             + f4abssum(c4) + f4abssum(c5) + f4abssum(c6) + f4abssum(c7);
    }

    // wave-64 reduction
    #pragma unroll
    for (int off = 32; off > 0; off >>= 1)
        acc += __shfl_down(acc, off, 64);

    __shared__ float wsum[4];
    const int lane = threadIdx.x & 63;
    const int wid  = threadIdx.x >> 6;
    if (lane == 0) wsum[wid] = acc;
    __syncthreads();

    if (threadIdx.x == 0) {
        float s = wsum[0] + wsum[1] + wsum[2] + wsum[3];
        atomicAdd(out, s);
    }
}

extern "C" void kernel_launch(void* const* d_in, const int* in_sizes, int n_in,
                              void* d_out, int out_size, void* d_ws, size_t ws_size,
                              hipStream_t stream) {
    const float* orig = (const float*)d_in[0];
    const float* pred = (const float*)d_in[1];
    float* out = (float*)d_out;

    const int nelem = in_sizes[0];          // 524288*3*64 = 100663296
    const int nwork = nelem / 32;           // 32 elements per work item (4 columns x 8 rows)

    // harness poisons d_out; zero it every call (graph-capturable memset node)
    hipMemsetAsync(out, 0, sizeof(float) * (size_t)out_size, stream);

    const int block = 256;
    int grid = 4096;
    const int needed = (nwork + block - 1) / block;
    if (needed < grid) grid = needed;

    satd_loss_kernel<<<grid, block, 0, stream>>>(orig, pred, out, nwork);
}